// Round 1
// baseline (1453.810 us; speedup 1.0000x reference)
//
#include <hip/hip_runtime.h>

// LSTM-like scan. x:[B,T] f32, W:[H+1,H] f32, b:[H] f32 -> out:[B,T,H] f32.
// B=256, T=2048, H=128.
// g_j = sum_i h_i*W[i,j] + x_t*W[H,j] + b_j ; sg = sigmoid(g);
// c = sg*(c+g); h = sg*c; out[b,t,:] = h.
//
// One block (128 thr = 2 waves) per batch row; 256 blocks = 1/CU.
// Thread j owns column j. W[:,j] pinned in 32 NAMED float4 VGPRs.
//
// ROUND FIX: previous build reported VGPR_Count=84 < 128 -> the compiler had
// sunk the "pinned" W loads back into the t-loop, re-fetching 64 KB/step/CU
// from L2 (~33.5 GB total, ~1 ms at the L2 roofline). The "+v" inline-asm
// keep-alives below make each W component a formal asm output, so it cannot
// be rematerialized by reloading -> values must stay live in VGPRs across
// the whole loop. Expect VGPR_Count >= 132 as proof the pin held.
//
// h double-buffered in LDS; inter-wave sync via raw s_barrier with only
// lgkmcnt(0) so per-step output stores are NOT drained in the serial chain.

#define BB 256
#define TT 2048
#define HH 128

#define LOADW(k) \
    float4 w##k = make_float4(W[(4*(k)+0)*HH + j], W[(4*(k)+1)*HH + j], \
                              W[(4*(k)+2)*HH + j], W[(4*(k)+3)*HH + j]);

// Pin w##k in VGPRs: "+v" marks each component as read-modify-write by the
// asm, so the compiler may not re-derive it later by reloading from memory.
#define KEEPW(k) \
    asm volatile("" : "+v"(w##k.x), "+v"(w##k.y), "+v"(w##k.z), "+v"(w##k.w));

#define FMASTEP(k) { \
    const float4 hv = hs4[(k)]; \
    a0 = fmaf(hv.x, w##k.x, a0); \
    a1 = fmaf(hv.y, w##k.y, a1); \
    a2 = fmaf(hv.z, w##k.z, a2); \
    a3 = fmaf(hv.w, w##k.w, a3); }

__global__ __launch_bounds__(HH, 1) void lstm_scan_kernel(
    const float* __restrict__ x,   // [B, T]
    const float* __restrict__ W,   // [H+1, H]
    const float* __restrict__ b,   // [H]
    float* __restrict__ out)       // [B, T, H]
{
    const int j = threadIdx.x;       // 0..127 : output column
    const int batch = blockIdx.x;    // 0..255

    __shared__ float xs[TT];         // 8 KB : this batch row's x
    __shared__ float hbuf[2][HH];    // 1 KB : double-buffered hidden state

    for (int t = j; t < TT; t += HH) {
        xs[t] = x[(size_t)batch * TT + t];
    }
    hbuf[0][j] = 0.0f;

    // W column j -> 32 named float4s (forced to stay in VGPRs).
    LOADW(0)  LOADW(1)  LOADW(2)  LOADW(3)  LOADW(4)  LOADW(5)  LOADW(6)  LOADW(7)
    LOADW(8)  LOADW(9)  LOADW(10) LOADW(11) LOADW(12) LOADW(13) LOADW(14) LOADW(15)
    LOADW(16) LOADW(17) LOADW(18) LOADW(19) LOADW(20) LOADW(21) LOADW(22) LOADW(23)
    LOADW(24) LOADW(25) LOADW(26) LOADW(27) LOADW(28) LOADW(29) LOADW(30) LOADW(31)

    KEEPW(0)  KEEPW(1)  KEEPW(2)  KEEPW(3)  KEEPW(4)  KEEPW(5)  KEEPW(6)  KEEPW(7)
    KEEPW(8)  KEEPW(9)  KEEPW(10) KEEPW(11) KEEPW(12) KEEPW(13) KEEPW(14) KEEPW(15)
    KEEPW(16) KEEPW(17) KEEPW(18) KEEPW(19) KEEPW(20) KEEPW(21) KEEPW(22) KEEPW(23)
    KEEPW(24) KEEPW(25) KEEPW(26) KEEPW(27) KEEPW(28) KEEPW(29) KEEPW(30) KEEPW(31)

    float wx   = W[HH * HH + j];
    float bias = b[j];
    asm volatile("" : "+v"(wx), "+v"(bias));

    float c = 0.0f;
    float* outp = out + (size_t)batch * TT * HH + j;

    __syncthreads();   // one-time: covers x staging + h init

    for (int t = 0; t < TT; ++t) {
        const int cur = t & 1;
        const float xt = xs[t];
        const float4* hs4 = (const float4*)(hbuf[cur]);

        float a0 = fmaf(xt, wx, bias);
        float a1 = 0.0f, a2 = 0.0f, a3 = 0.0f;
        FMASTEP(0)  FMASTEP(1)  FMASTEP(2)  FMASTEP(3)
        FMASTEP(4)  FMASTEP(5)  FMASTEP(6)  FMASTEP(7)
        FMASTEP(8)  FMASTEP(9)  FMASTEP(10) FMASTEP(11)
        FMASTEP(12) FMASTEP(13) FMASTEP(14) FMASTEP(15)
        FMASTEP(16) FMASTEP(17) FMASTEP(18) FMASTEP(19)
        FMASTEP(20) FMASTEP(21) FMASTEP(22) FMASTEP(23)
        FMASTEP(24) FMASTEP(25) FMASTEP(26) FMASTEP(27)
        FMASTEP(28) FMASTEP(29) FMASTEP(30) FMASTEP(31)

        const float g = (a0 + a1) + (a2 + a3);
        const float sg = 1.0f / (1.0f + __expf(-g));
        c = sg * (c + g);
        const float hn = sg * c;

        hbuf[cur ^ 1][j] = hn;       // next-step buffer
        outp[(size_t)t * HH] = hn;   // fire-and-forget (never drained below)

        // LDS-only sync: wait our ds ops, barrier. Global stores stay in
        // flight (plain __syncthreads would force vmcnt(0) each step).
        asm volatile("s_waitcnt lgkmcnt(0)\n\ts_barrier" ::: "memory");
    }
}

extern "C" void kernel_launch(void* const* d_in, const int* in_sizes, int n_in,
                              void* d_out, int out_size, void* d_ws, size_t ws_size,
                              hipStream_t stream) {
    const float* x = (const float*)d_in[0];
    const float* W = (const float*)d_in[1];
    const float* b = (const float*)d_in[2];
    float* out = (float*)d_out;

    lstm_scan_kernel<<<BB, HH, 0, stream>>>(x, W, b, out);
}

// Round 4
// 1256.402 us; speedup vs baseline: 1.1571x; 1.1571x over previous
//
#include <hip/hip_runtime.h>

// LSTM-like scan. x:[B,T] f32, W:[H+1,H] f32, b:[H] f32 -> out:[B,T,H] f32.
// B=256, T=2048, H=128.
// g_j = sum_i h_i*W[i,j] + x_t*W[H,j] + b_j ; sg = sigmoid(g);
// c = sg*(c+g); h = sg*c; out[b,t,:] = h.
//
// ROUND 4: K-split x4 (rounds 0/1 proved the allocator won't hold 128 W
// floats/thread: VGPR pinned at 84, ~64KB/step/CU W reload from L2 == the
// whole 1.3ms). 512 thr = 8 waves; wave w: rows 32q..32q+31 (q=w>>1),
// columns j=(w&1)*64+lane. 32 W floats/thread (8 named float4).
//
// SINGLE-BARRIER SCAN: no LDS hidden-state buffer at all. Lane l carries
// c[jj] and h[jj] (jj = 32q + (l&31)) in REGISTERS across steps; the MAC
// phase broadcasts h values from registers via v_readlane (constant lane
// ids). Per step: MACs -> partial for column j -> pb[t&1][q][j] ->
// lgkmcnt(0)+s_barrier -> each lane sums the 4 partials for its jj ->
// sigmoid/c/h update in-register -> 4 designated half-waves store out.
// pb is double-buffered; one barrier per step is sufficient (a wave cannot
// pass barrier t+1 until every wave has done its iter-t reads).
// Global output stores are fire-and-forget (never drained in the chain).

#define BB 256
#define TT 2048
#define HH 128
#define NT 512   // 8 waves

#define LOADW(k) \
    float4 w##k = make_float4(W[(kbase + 4*(k)+0)*HH + j], W[(kbase + 4*(k)+1)*HH + j], \
                              W[(kbase + 4*(k)+2)*HH + j], W[(kbase + 4*(k)+3)*HH + j]);

// Make W values asm-defined so they cannot be rematerialized by reloading.
#define KEEPW(k) \
    asm volatile("" : "+v"(w##k.x), "+v"(w##k.y), "+v"(w##k.z), "+v"(w##k.w));

// Broadcast h[kbase+i] from lane i of vh (lanes 0..31 hold the chunk).
#define RL(i) __uint_as_float(__builtin_amdgcn_readlane(__float_as_uint(vh), (i)))

#define MAC4(k) { \
    a0 = fmaf(RL(4*(k)+0), w##k.x, a0); \
    a1 = fmaf(RL(4*(k)+1), w##k.y, a1); \
    a2 = fmaf(RL(4*(k)+2), w##k.z, a2); \
    a3 = fmaf(RL(4*(k)+3), w##k.w, a3); }

__global__ __launch_bounds__(NT, 1) void lstm_scan_kernel(
    const float* __restrict__ x,   // [B, T]
    const float* __restrict__ W,   // [H+1, H]
    const float* __restrict__ b,   // [H]
    float* __restrict__ out)       // [B, T, H]
{
    const int tid   = threadIdx.x;
    const int lane  = tid & 63;
    const int wave  = tid >> 6;
    const int q     = wave >> 1;                // 0..3 : K chunk
    const int j     = ((wave & 1) << 6) | lane; // 0..127 : partial column
    const int kbase = q << 5;                   // first row of this chunk
    const int jj    = kbase + (lane & 31);      // per-lane state column
    const int batch = blockIdx.x;

    __shared__ float xs[TT];               // 8 KB : this batch row's x
    __shared__ float pb_raw[2 * 4 * HH];   // 4 KB : double-buffered partials
    volatile float* pb = pb_raw;

    for (int t = tid; t < TT; t += NT) {
        xs[t] = x[(size_t)batch * TT + t];
    }

    // W rows [32q, 32q+32) of column j -> 8 named float4s (32 VGPRs).
    LOADW(0) LOADW(1) LOADW(2) LOADW(3) LOADW(4) LOADW(5) LOADW(6) LOADW(7)
    KEEPW(0) KEEPW(1) KEEPW(2) KEEPW(3) KEEPW(4) KEEPW(5) KEEPW(6) KEEPW(7)

    // x-term + bias folded into exactly one K-chunk (q==0).
    const float wx   = (q == 0) ? W[HH * HH + j] : 0.0f;
    const float bias = (q == 0) ? b[j]           : 0.0f;

    float vh = 0.0f;   // h[jj]  (duplicated across lane halves)
    float c  = 0.0f;   // c[jj]
    const bool writer = ((wave & 1) == 0) && (lane < 32);
    float* outp = out + (size_t)batch * TT * HH + jj;

    __syncthreads();   // covers x staging

    for (int t = 0; t < TT; ++t) {
        const int buf = (t & 1) << 9;      // *4*HH

        // ---- MAC phase: partial for column j over rows kbase..kbase+31 ----
        float a0 = fmaf(xs[t], wx, bias);
        float a1 = 0.0f, a2 = 0.0f, a3 = 0.0f;
        MAC4(0) MAC4(1) MAC4(2) MAC4(3) MAC4(4) MAC4(5) MAC4(6) MAC4(7)
        const float part = (a0 + a1) + (a2 + a3);

        pb[buf + q * HH + j] = part;       // banks j%32 : conflict-free

        asm volatile("s_waitcnt lgkmcnt(0)" ::: "memory");
        __builtin_amdgcn_s_barrier();

        // ---- reduce + pointwise, redundantly per lane for its jj ----
        // 4 reads, 2-way same-address across lane halves (free broadcast).
        const float g = (pb[buf + jj] + pb[buf + HH + jj])
                      + (pb[buf + 2 * HH + jj] + pb[buf + 3 * HH + jj]);
        const float sg = 1.0f / (1.0f + __expf(-g));
        c  = sg * (c + g);
        vh = sg * c;                       // next step's h[jj], in-register

        if (writer) outp[(size_t)t * HH] = vh;   // fire-and-forget
    }
}

extern "C" void kernel_launch(void* const* d_in, const int* in_sizes, int n_in,
                              void* d_out, int out_size, void* d_ws, size_t ws_size,
                              hipStream_t stream) {
    const float* x = (const float*)d_in[0];
    const float* W = (const float*)d_in[1];
    const float* b = (const float*)d_in[2];
    float* out = (float*)d_out;

    lstm_scan_kernel<<<BB, NT, 0, stream>>>(x, W, b, out);
}